// Round 9
// baseline (207.709 us; speedup 1.0000x reference)
//
#include <hip/hip_runtime.h>

// Problem constants (match reference)
#define BB 8
#define CC 3
#define HH 1024
#define WW 1024
#define NS 15728        // int(1024*1024*0.015)
#define NG (NS / 4)     // 3932 int4 groups (NS % 4 == 0)

// Gaussian 5-tap, sigma=1.5, normalized
#define G0 0.1200784f
#define G1 0.2338808f
#define G2 0.2920816f

// ---------------------------------------------------------------------------
// Kernel 1: snow boxes -> per-batch bitmask [B][H][W/32], built per 32-col
// stripe in LDS (1 word/row, 4 KiB). 256 blocks (32 stripes x 8 batches).
// Spots scanned as int4 with one-group-ahead prefetch. No memset needed.
// (verified fast in rounds 3-8; unchanged)
// ---------------------------------------------------------------------------
#define NSTRIPE 32

__global__ __launch_bounds__(256) void snow_mask_kernel(
    const int* __restrict__ ys, const int* __restrict__ xs,
    const int* __restrict__ rs, unsigned int* __restrict__ mbits) {
  __shared__ unsigned int lm[HH];
  const int b = blockIdx.y;
  const int sx0 = blockIdx.x << 5;  // 32-col stripe
  const int tid = threadIdx.x;

  for (int i = tid; i < HH; i += 256) lm[i] = 0u;
  __syncthreads();

  const int4* __restrict__ y4 = (const int4*)(ys + b * NS);
  const int4* __restrict__ x4 = (const int4*)(xs + b * NS);
  const int4* __restrict__ r4 = (const int4*)(rs + b * NS);

  auto spot = [&](int y, int x, int r) {
    r += 1;  // radius in {1,2,3}
    int x0 = max(x - r, sx0), x1 = min(x + r, sx0 + 31);
    if (x0 > x1) return;  // box misses this stripe (~97% reject)
    int y0 = max(y - r, 0), y1 = min(y + r, HH - 1);
    unsigned m = (0xFFFFFFFFu << (x0 & 31)) & (0xFFFFFFFFu >> (31 - (x1 & 31)));
    for (int py = y0; py <= y1; ++py) atomicOr(&lm[py], m);
  };

  int g = tid;
  int4 Y = {0, 0, 0, 0}, X = {0, 0, 0, 0}, R = {0, 0, 0, 0};
  bool have = g < NG;
  if (have) { Y = y4[g]; X = x4[g]; R = r4[g]; }
  while (have) {
    int gn = g + 256;
    int4 Yn = {0, 0, 0, 0}, Xn = {0, 0, 0, 0}, Rn = {0, 0, 0, 0};
    bool haven = gn < NG;
    if (haven) { Yn = y4[gn]; Xn = x4[gn]; Rn = r4[gn]; }  // prefetch
    spot(Y.x, X.x, R.x);
    spot(Y.y, X.y, R.y);
    spot(Y.z, X.z, R.z);
    spot(Y.w, X.w, R.w);
    g = gn; Y = Yn; X = Xn; R = Rn; have = haven;
  }
  __syncthreads();

  unsigned int* dst = mbits + ((unsigned)(b * HH) << 5) + blockIdx.x;
  for (int i = tid; i < HH; i += 256) dst[i << 5] = lm[i];
}

// ---------------------------------------------------------------------------
// Kernel 2: masked-fill (0.95) + separable 5x5 Gaussian + clip, fused.
// Six measurements establish: per-wave delivered BW is pinned (~0.85 GB/s)
// no matter how the instruction stream is pipelined; aggregate BW moves ONLY
// with resident waves (round 4: 71% occ -> +33% BW). Round 9 buys occupancy
// at CONSTANT traffic shape: 128-thread blocks x 512 cols, RROWS=16 ->
// 3072 blocks = 12 blocks/CU all co-resident (~75% occ cap), vs 36% now.
// __launch_bounds__(128,4) keeps the VGPR cap at 128 (round 7's crash was
// the (128,8)=64-VGPR cap forcing reuse of in-flight asm load dests).
// Kernel body identical to round 8 (passed, absmax 0.0039, FETCH 62/WRITE 96).
// ---------------------------------------------------------------------------
#define RROWS 16
#define BTH 128          // threads per block (2 waves)
#define BCOLS 512        // cols per block (BTH*4)

template <int N>
__device__ __forceinline__ void wait_vmcnt() {
  asm volatile("s_waitcnt vmcnt(%0)" ::"n"(N) : "memory");
  __builtin_amdgcn_sched_barrier(0);
}

__device__ __forceinline__ void ld4(const float* p, float4& d) {
  asm volatile("global_load_dwordx4 %0, %1, off" : "=v"(d) : "v"(p));
}
__device__ __forceinline__ void ld2(const float* p, float2& d) {
  asm volatile("global_load_dwordx2 %0, %1, off" : "=v"(d) : "v"(p));
}
__device__ __forceinline__ void ld1(const unsigned* p, unsigned& d) {
  asm volatile("global_load_dword %0, %1, off" : "=v"(d) : "v"(p));
}

struct Row {
  float4 B;      // cols col..col+3
  float2 E;      // edge-lane halo (lane0: col-2,col-1; lane63: col+4,col+5)
  unsigned m0;   // mask word holding col..col+3
  unsigned m1;   // mask word holding E's bits
};

__global__ __launch_bounds__(BTH, 4) void snow_blur_kernel(
    const float* __restrict__ x, const unsigned int* __restrict__ mbits,
    float* __restrict__ out) {
  const int bz = blockIdx.z;        // b*CC + c
  const int b = bz / CC;
  const int gy0 = blockIdx.y * RROWS;
  const int tid = threadIdx.x;
  const int col = blockIdx.x * BCOLS + (tid << 2);
  const int lane = tid & 63;        // wave covers 256 contiguous cols

  const float* __restrict__ xp = x + (size_t)bz * (HH * WW);
  const unsigned int* __restrict__ mb = mbits + ((unsigned)(b * HH) << 5);

  // loop-invariant per-lane geometry
  const int s5 = col & 31;                        // bit pos of col in m0
  const int w0 = col >> 5;                        // mask word of own cols
  const bool l0 = (lane == 0), l63 = (lane == 63);
  // edge-halo column (middle lanes: own col -> L1-hit duplicate)
  const int eCol = l0 ? max(col - 2, 0) : (l63 ? min(col + 4, WW - 2) : col);
  const int ew = eCol >> 5;
  const int eshift = eCol & 31;
  // OOB sentinels: image edge -> halo is conv zero-padding
  const unsigned eoob = (l0 && col == 0) ? 16u
                        : ((l63 && col == WW - 4) ? 16u : 0u);

  // issue one row's 4 loads (asm: issue order fixed, cannot be sunk)
  auto issue = [&](int gy, Row& rw) {
    int gyc = min(max(gy, 0), HH - 1);
    const float* rp = xp + ((size_t)gyc << 10);
    const unsigned* mrow = mb + (gyc << 5);
    ld4(rp + col, rw.B);
    ld2(rp + eCol, rw.E);
    ld1(mrow + w0, rw.m0);
    ld1(mrow + ew, rw.m1);
  };

  // consume one staged row -> horizontal 5-tap for 4 cols
  auto consume = [&](const Row& rw, unsigned ro) {
    unsigned bB = ((rw.m0 >> s5) & 0xFu) | ro;
    float4 fB;
    fB.x = (bB & 1u) ? 0.95f : rw.B.x;
    fB.y = (bB & 2u) ? 0.95f : rw.B.y;
    fB.z = (bB & 4u) ? 0.95f : rw.B.z;
    fB.w = (bB & 8u) ? 0.95f : rw.B.w;
    if (bB & 16u) { fB.x = 0.f; fB.y = 0.f; fB.z = 0.f; fB.w = 0.f; }
    // edge-lane fixed halo
    unsigned bE = ((rw.m1 >> eshift) & 3u) | ro | eoob;
    float2 fE;
    fE.x = (bE & 1u) ? 0.95f : rw.E.x;
    fE.y = (bE & 2u) ? 0.95f : rw.E.y;
    if (bE & 16u) { fE.x = 0.f; fE.y = 0.f; }
    // halos from neighbor lanes' POST-FILL values (no loads)
    float lz = __shfl_up(fB.z, 1, 64);    // col-2
    float lw = __shfl_up(fB.w, 1, 64);    // col-1
    float rx = __shfl_down(fB.x, 1, 64);  // col+4
    float ry = __shfl_down(fB.y, 1, 64);  // col+5
    float2 fL, fR;
    fL.x = l0 ? fE.x : lz;
    fL.y = l0 ? fE.y : lw;
    fR.x = l63 ? fE.x : rx;
    fR.y = l63 ? fE.y : ry;
    float4 h;
    h.x = G0 * (fL.x + fB.z) + G1 * (fL.y + fB.y) + G2 * fB.x;
    h.y = G0 * (fL.y + fB.w) + G1 * (fB.x + fB.z) + G2 * fB.y;
    h.z = G0 * (fB.x + fR.x) + G1 * (fB.y + fB.w) + G2 * fB.z;
    h.w = G0 * (fB.y + fR.y) + G1 * (fB.z + fR.x) + G2 * fB.w;
    return h;
  };

  auto rof = [&](int gy) { return (gy < 0 || gy >= HH) ? 16u : 0u; };

  // ---- prologue: issue all 7 rows (28 loads), then counted consumes ----
  Row ra, rb, rc, rd, s0, s1, s2;
  issue(gy0 - 2, ra);
  issue(gy0 - 1, rb);
  issue(gy0 + 0, rc);
  issue(gy0 + 1, rd);
  issue(gy0 + 2, s0);
  issue(gy0 + 3, s1);
  issue(gy0 + 4, s2);
  wait_vmcnt<24>();
  float4 h0 = consume(ra, rof(gy0 - 2));
  wait_vmcnt<20>();
  float4 h1 = consume(rb, rof(gy0 - 1));
  wait_vmcnt<16>();
  float4 h2 = consume(rc, 0u);   // gy0..gy0+1 always in range
  wait_vmcnt<12>();
  float4 h3 = consume(rd, 0u);

  float* op = out + (size_t)bz * (HH * WW) + ((size_t)gy0 << 10) + col;

  // wait counts (4 loads/row, 1 store/iter, in-order vmcnt retirement):
  // k=0:12 k=1:13 k=2:14 k=3..12:15 k=13:11 k=14:7 k=15:3
#define STEP(K, WN)                                                     \
  {                                                                     \
    Row nr{};                                                           \
    if ((K) < RROWS - 3) issue(gy0 + 5 + (K), nr);                      \
    wait_vmcnt<WN>();                                                   \
    float4 h4 = consume(s0, rof(gy0 + 2 + (K)));                        \
    float4 sv;                                                          \
    sv.x = G0 * (h0.x + h4.x) + G1 * (h1.x + h3.x) + G2 * h2.x;         \
    sv.y = G0 * (h0.y + h4.y) + G1 * (h1.y + h3.y) + G2 * h2.y;         \
    sv.z = G0 * (h0.z + h4.z) + G1 * (h1.z + h3.z) + G2 * h2.z;         \
    sv.w = G0 * (h0.w + h4.w) + G1 * (h1.w + h3.w) + G2 * h2.w;         \
    sv.x = fminf(fmaxf(sv.x, 0.f), 1.f);                                \
    sv.y = fminf(fmaxf(sv.y, 0.f), 1.f);                                \
    sv.z = fminf(fmaxf(sv.z, 0.f), 1.f);                                \
    sv.w = fminf(fmaxf(sv.w, 0.f), 1.f);                                \
    *(float4*)op = sv;                                                  \
    op += WW;                                                           \
    s0 = s1; s1 = s2; s2 = nr;                                          \
    h0 = h1; h1 = h2; h2 = h3; h3 = h4;                                 \
  }

  STEP(0, 12)
  STEP(1, 13)
  STEP(2, 14)
  STEP(3, 15)
  STEP(4, 15)
  STEP(5, 15)
  STEP(6, 15)
  STEP(7, 15)
  STEP(8, 15)
  STEP(9, 15)
  STEP(10, 15)
  STEP(11, 15)
  STEP(12, 15)
  STEP(13, 11)
  STEP(14, 7)
  STEP(15, 3)
#undef STEP
}

// ---------------------------------------------------------------------------
extern "C" void kernel_launch(void* const* d_in, const int* in_sizes, int n_in,
                              void* d_out, int out_size, void* d_ws, size_t ws_size,
                              hipStream_t stream) {
  const float* x = (const float*)d_in[0];
  const int* ys = (const int*)d_in[1];
  const int* xs = (const int*)d_in[2];
  const int* rs = (const int*)d_in[3];
  float* out = (float*)d_out;

  unsigned int* mbits = (unsigned int*)d_ws;  // B*H*W/8 = 1 MiB
  // no memset: mask kernel fully overwrites every word of mbits

  dim3 mgrid(NSTRIPE, BB);
  snow_mask_kernel<<<mgrid, 256, 0, stream>>>(ys, xs, rs, mbits);

  dim3 grid(WW / BCOLS, HH / RROWS, BB * CC);
  snow_blur_kernel<<<grid, BTH, 0, stream>>>(x, mbits, out);
}

// Round 10
// 203.620 us; speedup vs baseline: 1.0201x; 1.0201x over previous
//
#include <hip/hip_runtime.h>

// Problem constants (match reference)
#define BB 8
#define CC 3
#define HH 1024
#define WW 1024
#define NS 15728        // int(1024*1024*0.015)
#define NG (NS / 4)     // 3932 int4 groups (NS % 4 == 0)

// Gaussian 5-tap, sigma=1.5, normalized
#define G0 0.1200784f
#define G1 0.2338808f
#define G2 0.2920816f

// ---------------------------------------------------------------------------
// Kernel 1: snow boxes -> per-batch bitmask [B][H][W/32], built per 32-col
// stripe in LDS (1 word/row, 4 KiB). 256 blocks (32 stripes x 8 batches).
// Spots scanned as int4 with one-group-ahead prefetch. No memset needed.
// (verified fast in rounds 3-9; unchanged)
// ---------------------------------------------------------------------------
#define NSTRIPE 32

__global__ __launch_bounds__(256) void snow_mask_kernel(
    const int* __restrict__ ys, const int* __restrict__ xs,
    const int* __restrict__ rs, unsigned int* __restrict__ mbits) {
  __shared__ unsigned int lm[HH];
  const int b = blockIdx.y;
  const int sx0 = blockIdx.x << 5;  // 32-col stripe
  const int tid = threadIdx.x;

  for (int i = tid; i < HH; i += 256) lm[i] = 0u;
  __syncthreads();

  const int4* __restrict__ y4 = (const int4*)(ys + b * NS);
  const int4* __restrict__ x4 = (const int4*)(xs + b * NS);
  const int4* __restrict__ r4 = (const int4*)(rs + b * NS);

  auto spot = [&](int y, int x, int r) {
    r += 1;  // radius in {1,2,3}
    int x0 = max(x - r, sx0), x1 = min(x + r, sx0 + 31);
    if (x0 > x1) return;  // box misses this stripe (~97% reject)
    int y0 = max(y - r, 0), y1 = min(y + r, HH - 1);
    unsigned m = (0xFFFFFFFFu << (x0 & 31)) & (0xFFFFFFFFu >> (31 - (x1 & 31)));
    for (int py = y0; py <= y1; ++py) atomicOr(&lm[py], m);
  };

  int g = tid;
  int4 Y = {0, 0, 0, 0}, X = {0, 0, 0, 0}, R = {0, 0, 0, 0};
  bool have = g < NG;
  if (have) { Y = y4[g]; X = x4[g]; R = r4[g]; }
  while (have) {
    int gn = g + 256;
    int4 Yn = {0, 0, 0, 0}, Xn = {0, 0, 0, 0}, Rn = {0, 0, 0, 0};
    bool haven = gn < NG;
    if (haven) { Yn = y4[gn]; Xn = x4[gn]; Rn = r4[gn]; }  // prefetch
    spot(Y.x, X.x, R.x);
    spot(Y.y, X.y, R.y);
    spot(Y.z, X.z, R.z);
    spot(Y.w, X.w, R.w);
    g = gn; Y = Yn; X = Xn; R = Rn; have = haven;
  }
  __syncthreads();

  unsigned int* dst = mbits + ((unsigned)(b * HH) << 5) + blockIdx.x;
  for (int i = tid; i < HH; i += 256) dst[i << 5] = lm[i];
}

// ---------------------------------------------------------------------------
// Kernel 2: masked-fill (0.95) + separable 5x5 Gaussian + clip, fused.
// ROOT CAUSE (rounds 3-9): any VGPR-destination load pipeline gets collapsed
// by the register allocator (coalesces ~70 needed dest regs into ~44, and the
// post-RA waitcnt pass serializes on every reuse) -> ~1 load in flight/wave,
// ~2.6 TB/s, invariant across 5 source-level variants. Escape: stage via
// __builtin_amdgcn_global_load_lds (NO VGPR dest -> nothing to coalesce).
// Tile 256 cols x 32 rows, 4 waves: each wave stages 9 image rows (one
// width-16 instr = 64 lanes x 16 B = one 1 KB row) + gathers x-halo/mask
// words via width-4 per-lane-addressed instrs into linear LDS. One barrier,
// then consume is pure LDS+VALU (round-8 verified arithmetic, loads->ds_read,
// shfl x-halo). LDS 39.9 KB -> 4 blocks/CU; ~150 KB DMA in flight per CU.
// ---------------------------------------------------------------------------
#define TCOLS 256
#define TROWS 32
#define SROWS 36   // TROWS + 4 halo rows

__device__ __forceinline__ void gl_lds16(const float* g, float* l) {
  __builtin_amdgcn_global_load_lds(
      (const __attribute__((address_space(1))) void*)g,
      (__attribute__((address_space(3))) void*)l, 16, 0, 0);
}
__device__ __forceinline__ void gl_lds4(const void* g, void* l) {
  __builtin_amdgcn_global_load_lds(
      (const __attribute__((address_space(1))) void*)g,
      (__attribute__((address_space(3))) void*)l, 4, 0, 0);
}

__global__ __launch_bounds__(256, 4) void snow_blur_kernel(
    const float* __restrict__ x, const unsigned int* __restrict__ mbits,
    float* __restrict__ out) {
  __shared__ float s_img[SROWS * TCOLS];   // 36 KB, row slot = 1 KB linear
  __shared__ float s_halo[192];            // [s*4+j]: j=0,1 left; 2,3 right
  __shared__ unsigned s_msk[SROWS * 16];   // [s*16+j], j=0..9 = words w0-1..w0+8

  const int bz = blockIdx.z;        // b*CC + c
  const int b = bz / CC;
  const int gy0 = blockIdx.y * TROWS;
  const int col0 = blockIdx.x * TCOLS;
  const int tid = threadIdx.x;
  const int wv = tid >> 6;
  const int lane = tid & 63;

  const float* __restrict__ xp = x + (size_t)bz * (HH * WW);
  const unsigned int* __restrict__ mb = mbits + ((unsigned)(b * HH) << 5);
  const int w0b = col0 >> 5;

  // ---- stage phase: all loads are LDS-DMA (no VGPR dest) ----
  // image rows: wave wv stages slots wv, wv+4, ..., wv+32 (9 rows)
#pragma unroll
  for (int i = 0; i < 9; ++i) {
    int s = wv + (i << 2);
    int gy = min(max(gy0 - 2 + s, 0), HH - 1);
    gl_lds16(xp + ((size_t)gy << 10) + col0 + (lane << 2), &s_img[s * TCOLS]);
  }
  if (wv == 0) {
    // x-halo gather: e = s*4+j, j in {0,1}: cols col0-2,col0-1; {2,3}: +256,+257
#pragma unroll
    for (int i = 0; i < 3; ++i) {
      int e = (i << 6) + lane;
      int s = min(e >> 2, SROWS - 1);
      int j = e & 3;
      int gy = min(max(gy0 - 2 + s, 0), HH - 1);
      int cc = (j < 2) ? (col0 - 2 + j) : (col0 + 254 + j);
      cc = min(max(cc, 0), WW - 1);
      gl_lds4(xp + ((size_t)gy << 10) + cc, &s_halo[i << 6]);
    }
  } else {
    // mask gather: e = s*16+j, j valid 0..9 -> word w0b-1+j (clamped); dups ok
#pragma unroll
    for (int i = 0; i < 3; ++i) {
      int n = (wv - 1) * 3 + i;   // 0..8, 9*64 = 576 = SROWS*16
      int e = (n << 6) + lane;
      int s = e >> 4;
      int j = e & 15;
      int gy = min(max(gy0 - 2 + s, 0), HH - 1);
      int widx = min(max(w0b - 1 + j, 0), 31);
      gl_lds4(mb + (gy << 5) + widx, &s_msk[n << 6]);
    }
  }
  __syncthreads();   // drains vmcnt (DMA) before any LDS read

  // ---- consume phase: pure LDS + VALU (round-8 verified arithmetic) ----
  const bool l0 = (lane == 0), l63 = (lane == 63);
  const int col = col0 + (lane << 2);
  const unsigned eoob = (l0 && col0 == 0) ? 16u
                        : ((l63 && col == WW - 4) ? 16u : 0u);
  const int s5 = (lane & 7) << 2;     // bit pos of own 4 cols in own word
  const int mj = 1 + (lane >> 3);     // own mask word slot
  const int ej = l63 ? 9 : 0;         // edge mask word slot
  const int eshift = l63 ? 0 : 30;    // edge bits position
  const int ehw = l63 ? 2 : 0;        // edge halo float2 slot

  auto hrow = [&](int s) {
    int gr = gy0 - 2 + s;
    unsigned ro = (gr < 0 || gr >= HH) ? 16u : 0u;
    float4 B = *(const float4*)&s_img[s * TCOLS + (lane << 2)];
    unsigned mw = s_msk[(s << 4) + mj];
    unsigned bB = ((mw >> s5) & 0xFu) | ro;
    float4 fB;
    fB.x = (bB & 1u) ? 0.95f : B.x;
    fB.y = (bB & 2u) ? 0.95f : B.y;
    fB.z = (bB & 4u) ? 0.95f : B.z;
    fB.w = (bB & 8u) ? 0.95f : B.w;
    if (bB & 16u) { fB.x = 0.f; fB.y = 0.f; fB.z = 0.f; fB.w = 0.f; }
    unsigned emw = s_msk[(s << 4) + ej];
    unsigned bE = ((emw >> eshift) & 3u) | ro | eoob;
    float2 fE = *(const float2*)&s_halo[(s << 2) + ehw];
    fE.x = (bE & 1u) ? 0.95f : fE.x;
    fE.y = (bE & 2u) ? 0.95f : fE.y;
    if (bE & 16u) { fE.x = 0.f; fE.y = 0.f; }
    // halos from neighbor lanes' POST-FILL values
    float lz = __shfl_up(fB.z, 1, 64);    // col-2
    float lw = __shfl_up(fB.w, 1, 64);    // col-1
    float rx = __shfl_down(fB.x, 1, 64);  // col+4
    float ry = __shfl_down(fB.y, 1, 64);  // col+5
    float2 fL, fR;
    fL.x = l0 ? fE.x : lz;
    fL.y = l0 ? fE.y : lw;
    fR.x = l63 ? fE.x : rx;
    fR.y = l63 ? fE.y : ry;
    float4 h;
    h.x = G0 * (fL.x + fB.z) + G1 * (fL.y + fB.y) + G2 * fB.x;
    h.y = G0 * (fL.y + fB.w) + G1 * (fB.x + fB.z) + G2 * fB.y;
    h.z = G0 * (fB.x + fR.x) + G1 * (fB.y + fB.w) + G2 * fB.z;
    h.w = G0 * (fB.y + fR.y) + G1 * (fB.z + fR.x) + G2 * fB.w;
    return h;
  };

  // wave wv outputs rows gy0 + wv*8 + k, k in [0,8): slots sbase+2..sbase+9
  const int sbase = wv << 3;
  float4 h0 = hrow(sbase + 0);
  float4 h1 = hrow(sbase + 1);
  float4 h2 = hrow(sbase + 2);
  float4 h3 = hrow(sbase + 3);

  float* op = out + (size_t)bz * (HH * WW) +
              ((size_t)(gy0 + (wv << 3)) << 10) + col;
#pragma unroll
  for (int k = 0; k < 8; ++k) {
    float4 h4 = hrow(sbase + 4 + k);
    float4 sv;
    sv.x = G0 * (h0.x + h4.x) + G1 * (h1.x + h3.x) + G2 * h2.x;
    sv.y = G0 * (h0.y + h4.y) + G1 * (h1.y + h3.y) + G2 * h2.y;
    sv.z = G0 * (h0.z + h4.z) + G1 * (h1.z + h3.z) + G2 * h2.z;
    sv.w = G0 * (h0.w + h4.w) + G1 * (h1.w + h3.w) + G2 * h2.w;
    sv.x = fminf(fmaxf(sv.x, 0.f), 1.f);
    sv.y = fminf(fmaxf(sv.y, 0.f), 1.f);
    sv.z = fminf(fmaxf(sv.z, 0.f), 1.f);
    sv.w = fminf(fmaxf(sv.w, 0.f), 1.f);
    *(float4*)op = sv;
    op += WW;
    h0 = h1; h1 = h2; h2 = h3; h3 = h4;
  }
}

// ---------------------------------------------------------------------------
extern "C" void kernel_launch(void* const* d_in, const int* in_sizes, int n_in,
                              void* d_out, int out_size, void* d_ws, size_t ws_size,
                              hipStream_t stream) {
  const float* x = (const float*)d_in[0];
  const int* ys = (const int*)d_in[1];
  const int* xs = (const int*)d_in[2];
  const int* rs = (const int*)d_in[3];
  float* out = (float*)d_out;

  unsigned int* mbits = (unsigned int*)d_ws;  // B*H*W/8 = 1 MiB
  // no memset: mask kernel fully overwrites every word of mbits

  dim3 mgrid(NSTRIPE, BB);
  snow_mask_kernel<<<mgrid, 256, 0, stream>>>(ys, xs, rs, mbits);

  dim3 grid(WW / TCOLS, HH / TROWS, BB * CC);
  snow_blur_kernel<<<grid, 256, 0, stream>>>(x, mbits, out);
}

// Round 11
// 203.001 us; speedup vs baseline: 1.0232x; 1.0030x over previous
//
#include <hip/hip_runtime.h>

// Problem constants (match reference)
#define BB 8
#define CC 3
#define HH 1024
#define WW 1024
#define NS 15728        // int(1024*1024*0.015)
#define NG (NS / 4)     // 3932 int4 groups (NS % 4 == 0)

// Gaussian 5-tap, sigma=1.5, normalized
#define G0 0.1200784f
#define G1 0.2338808f
#define G2 0.2920816f

// ---------------------------------------------------------------------------
// Kernel 1: snow boxes -> per-batch bitmask [B][H][W/32], built per 32-col
// stripe in LDS (1 word/row, 4 KiB). 256 blocks (32 stripes x 8 batches).
// Spots scanned as int4 with one-group-ahead prefetch. No memset needed.
// (verified fast in rounds 3-10; unchanged)
// ---------------------------------------------------------------------------
#define NSTRIPE 32

__global__ __launch_bounds__(256) void snow_mask_kernel(
    const int* __restrict__ ys, const int* __restrict__ xs,
    const int* __restrict__ rs, unsigned int* __restrict__ mbits) {
  __shared__ unsigned int lm[HH];
  const int b = blockIdx.y;
  const int sx0 = blockIdx.x << 5;  // 32-col stripe
  const int tid = threadIdx.x;

  for (int i = tid; i < HH; i += 256) lm[i] = 0u;
  __syncthreads();

  const int4* __restrict__ y4 = (const int4*)(ys + b * NS);
  const int4* __restrict__ x4 = (const int4*)(xs + b * NS);
  const int4* __restrict__ r4 = (const int4*)(rs + b * NS);

  auto spot = [&](int y, int x, int r) {
    r += 1;  // radius in {1,2,3}
    int x0 = max(x - r, sx0), x1 = min(x + r, sx0 + 31);
    if (x0 > x1) return;  // box misses this stripe (~97% reject)
    int y0 = max(y - r, 0), y1 = min(y + r, HH - 1);
    unsigned m = (0xFFFFFFFFu << (x0 & 31)) & (0xFFFFFFFFu >> (31 - (x1 & 31)));
    for (int py = y0; py <= y1; ++py) atomicOr(&lm[py], m);
  };

  int g = tid;
  int4 Y = {0, 0, 0, 0}, X = {0, 0, 0, 0}, R = {0, 0, 0, 0};
  bool have = g < NG;
  if (have) { Y = y4[g]; X = x4[g]; R = r4[g]; }
  while (have) {
    int gn = g + 256;
    int4 Yn = {0, 0, 0, 0}, Xn = {0, 0, 0, 0}, Rn = {0, 0, 0, 0};
    bool haven = gn < NG;
    if (haven) { Yn = y4[gn]; Xn = x4[gn]; Rn = r4[gn]; }  // prefetch
    spot(Y.x, X.x, R.x);
    spot(Y.y, X.y, R.y);
    spot(Y.z, X.z, R.z);
    spot(Y.w, X.w, R.w);
    g = gn; Y = Yn; X = Xn; R = Rn; have = haven;
  }
  __syncthreads();

  unsigned int* dst = mbits + ((unsigned)(b * HH) << 5) + blockIdx.x;
  for (int i = tid; i < HH; i += 256) dst[i << 5] = lm[i];
}

// ---------------------------------------------------------------------------
// Kernel 2: masked-fill (0.95) + separable 5x5 Gaussian + clip, fused.
// Round-10 structure (LDS-DMA staging via global_load_lds: no VGPR load
// dests -> allocator can't collapse the pipeline) was the first win and
// raised per-wave BW to 1.1 GB/s; its limit was occupancy (LDS 39.9 KB ->
// 4 blocks/CU, measured 31%). Cross-round model: BW ~ 1 GB/s x resident
// waves. Round 11: SAME structure, TROWS 32->16 (SROWS 20) -> LDS 22.3 KB
// -> 7 blocks/CU = 28 waves (87% cap). Traffic shape preserved (256-wide
// strips, y-halo L3-resident; round-10 verified FETCH 68/WRITE 96).
// ---------------------------------------------------------------------------
#define TCOLS 256
#define TROWS 16
#define SROWS 20   // TROWS + 4 halo rows

__device__ __forceinline__ void gl_lds16(const float* g, float* l) {
  __builtin_amdgcn_global_load_lds(
      (const __attribute__((address_space(1))) void*)g,
      (__attribute__((address_space(3))) void*)l, 16, 0, 0);
}
__device__ __forceinline__ void gl_lds4(const void* g, void* l) {
  __builtin_amdgcn_global_load_lds(
      (const __attribute__((address_space(1))) void*)g,
      (__attribute__((address_space(3))) void*)l, 4, 0, 0);
}

__global__ __launch_bounds__(256, 4) void snow_blur_kernel(
    const float* __restrict__ x, const unsigned int* __restrict__ mbits,
    float* __restrict__ out) {
  __shared__ float s_img[SROWS * TCOLS];   // 20 KB, row slot = 1 KB linear
  __shared__ float s_halo[128];            // [s*4+j]: j=0,1 left; 2,3 right (80 used)
  __shared__ unsigned s_msk[SROWS * 16];   // [s*16+j], j=0..9 = words w0b-1..w0b+8

  const int bz = blockIdx.z;        // b*CC + c
  const int b = bz / CC;
  const int gy0 = blockIdx.y * TROWS;
  const int col0 = blockIdx.x * TCOLS;
  const int tid = threadIdx.x;
  const int wv = tid >> 6;
  const int lane = tid & 63;

  const float* __restrict__ xp = x + (size_t)bz * (HH * WW);
  const unsigned int* __restrict__ mb = mbits + ((unsigned)(b * HH) << 5);
  const int w0b = col0 >> 5;

  // ---- stage phase: all loads are LDS-DMA (no VGPR dest) ----
  // image rows: wave wv stages slots wv, wv+4, ..., wv+16 (5 rows)
#pragma unroll
  for (int i = 0; i < 5; ++i) {
    int s = wv + (i << 2);
    int gy = min(max(gy0 - 2 + s, 0), HH - 1);
    gl_lds16(xp + ((size_t)gy << 10) + col0 + (lane << 2), &s_img[s * TCOLS]);
  }
  if (wv == 0) {
    // x-halo gather: e = s*4+j, j in {0,1}: cols col0-2,col0-1; {2,3}: +256,+257
#pragma unroll
    for (int i = 0; i < 2; ++i) {
      int e = (i << 6) + lane;
      int s = min(e >> 2, SROWS - 1);   // e>=80: dup, lands in pad area
      int j = e & 3;
      int gy = min(max(gy0 - 2 + s, 0), HH - 1);
      int cc = (j < 2) ? (col0 - 2 + j) : (col0 + 254 + j);
      cc = min(max(cc, 0), WW - 1);
      gl_lds4(xp + ((size_t)gy << 10) + cc, &s_halo[i << 6]);
    }
  } else {
    // mask gather: e = s*16+j, j valid 0..9 -> word w0b-1+j (clamped); dups ok
#pragma unroll
    for (int i = 0; i < 2; ++i) {
      int n = (wv - 1) * 2 + i;   // 0..5; groups 0..4 cover 320 = SROWS*16
      if (n < 5) {
        int e = (n << 6) + lane;
        int s = e >> 4;
        int j = e & 15;
        int gy = min(max(gy0 - 2 + s, 0), HH - 1);
        int widx = min(max(w0b - 1 + j, 0), 31);
        gl_lds4(mb + (gy << 5) + widx, &s_msk[n << 6]);
      }
    }
  }
  __syncthreads();   // drains vmcnt (DMA) before any LDS read

  // ---- consume phase: pure LDS + VALU (round-8/10 verified arithmetic) ----
  const bool l0 = (lane == 0), l63 = (lane == 63);
  const int col = col0 + (lane << 2);
  const unsigned eoob = (l0 && col0 == 0) ? 16u
                        : ((l63 && col == WW - 4) ? 16u : 0u);
  const int s5 = (lane & 7) << 2;     // bit pos of own 4 cols in own word
  const int mj = 1 + (lane >> 3);     // own mask word slot
  const int ej = l63 ? 9 : 0;         // edge mask word slot
  const int eshift = l63 ? 0 : 30;    // edge bits position
  const int ehw = l63 ? 2 : 0;        // edge halo float2 slot

  auto hrow = [&](int s) {
    int gr = gy0 - 2 + s;
    unsigned ro = (gr < 0 || gr >= HH) ? 16u : 0u;
    float4 B = *(const float4*)&s_img[s * TCOLS + (lane << 2)];
    unsigned mw = s_msk[(s << 4) + mj];
    unsigned bB = ((mw >> s5) & 0xFu) | ro;
    float4 fB;
    fB.x = (bB & 1u) ? 0.95f : B.x;
    fB.y = (bB & 2u) ? 0.95f : B.y;
    fB.z = (bB & 4u) ? 0.95f : B.z;
    fB.w = (bB & 8u) ? 0.95f : B.w;
    if (bB & 16u) { fB.x = 0.f; fB.y = 0.f; fB.z = 0.f; fB.w = 0.f; }
    unsigned emw = s_msk[(s << 4) + ej];
    unsigned bE = ((emw >> eshift) & 3u) | ro | eoob;
    float2 fE = *(const float2*)&s_halo[(s << 2) + ehw];
    fE.x = (bE & 1u) ? 0.95f : fE.x;
    fE.y = (bE & 2u) ? 0.95f : fE.y;
    if (bE & 16u) { fE.x = 0.f; fE.y = 0.f; }
    // halos from neighbor lanes' POST-FILL values
    float lz = __shfl_up(fB.z, 1, 64);    // col-2
    float lw = __shfl_up(fB.w, 1, 64);    // col-1
    float rx = __shfl_down(fB.x, 1, 64);  // col+4
    float ry = __shfl_down(fB.y, 1, 64);  // col+5
    float2 fL, fR;
    fL.x = l0 ? fE.x : lz;
    fL.y = l0 ? fE.y : lw;
    fR.x = l63 ? fE.x : rx;
    fR.y = l63 ? fE.y : ry;
    float4 h;
    h.x = G0 * (fL.x + fB.z) + G1 * (fL.y + fB.y) + G2 * fB.x;
    h.y = G0 * (fL.y + fB.w) + G1 * (fB.x + fB.z) + G2 * fB.y;
    h.z = G0 * (fB.x + fR.x) + G1 * (fB.y + fB.w) + G2 * fB.z;
    h.w = G0 * (fB.y + fR.y) + G1 * (fB.z + fR.x) + G2 * fB.w;
    return h;
  };

  // wave wv outputs rows gy0 + wv*4 + k, k in [0,4): slots sbase..sbase+7
  const int sbase = wv << 2;
  float4 h0 = hrow(sbase + 0);
  float4 h1 = hrow(sbase + 1);
  float4 h2 = hrow(sbase + 2);
  float4 h3 = hrow(sbase + 3);

  float* op = out + (size_t)bz * (HH * WW) +
              ((size_t)(gy0 + (wv << 2)) << 10) + col;
#pragma unroll
  for (int k = 0; k < 4; ++k) {
    float4 h4 = hrow(sbase + 4 + k);
    float4 sv;
    sv.x = G0 * (h0.x + h4.x) + G1 * (h1.x + h3.x) + G2 * h2.x;
    sv.y = G0 * (h0.y + h4.y) + G1 * (h1.y + h3.y) + G2 * h2.y;
    sv.z = G0 * (h0.z + h4.z) + G1 * (h1.z + h3.z) + G2 * h2.z;
    sv.w = G0 * (h0.w + h4.w) + G1 * (h1.w + h3.w) + G2 * h2.w;
    sv.x = fminf(fmaxf(sv.x, 0.f), 1.f);
    sv.y = fminf(fmaxf(sv.y, 0.f), 1.f);
    sv.z = fminf(fmaxf(sv.z, 0.f), 1.f);
    sv.w = fminf(fmaxf(sv.w, 0.f), 1.f);
    *(float4*)op = sv;
    op += WW;
    h0 = h1; h1 = h2; h2 = h3; h3 = h4;
  }
}

// ---------------------------------------------------------------------------
extern "C" void kernel_launch(void* const* d_in, const int* in_sizes, int n_in,
                              void* d_out, int out_size, void* d_ws, size_t ws_size,
                              hipStream_t stream) {
  const float* x = (const float*)d_in[0];
  const int* ys = (const int*)d_in[1];
  const int* xs = (const int*)d_in[2];
  const int* rs = (const int*)d_in[3];
  float* out = (float*)d_out;

  unsigned int* mbits = (unsigned int*)d_ws;  // B*H*W/8 = 1 MiB
  // no memset: mask kernel fully overwrites every word of mbits

  dim3 mgrid(NSTRIPE, BB);
  snow_mask_kernel<<<mgrid, 256, 0, stream>>>(ys, xs, rs, mbits);

  dim3 grid(WW / TCOLS, HH / TROWS, BB * CC);
  snow_blur_kernel<<<grid, 256, 0, stream>>>(x, mbits, out);
}